// Round 6
// baseline (84.580 us; speedup 1.0000x reference)
//
#include <hip/hip_runtime.h>
#include <hip/hip_bf16.h>

// Problem constants: B=128, C=21, L=2048, W=32, S=8, O=16, NW=252, NK=4032, K=672
#define Bb   128
#define Cc   21
#define Ll   2048
#define Ss   8
#define Oo   16
#define NWw  252
#define NKk  4032
#define Kk   672
#define KP   680   // LDS pitch (bf16): 85 x 16B granules/row, conflict-light b128

typedef __attribute__((ext_vector_type(8))) short  short8;  // 8 bf16 = 4 VGPRs
typedef __attribute__((ext_vector_type(4))) float  f32x4;

static __device__ __forceinline__ unsigned short f2bf(float f) {
    union { __hip_bfloat16 h; unsigned short u; } cv;
    cv.h = __float2bfloat16(f);
    return cv.u;
}

// ---- Pass 1: fp32 -> bf16 for BOTH x (22->11 MB) and w (10.8->5.4 MB). ----
// Pure stream, ~49 MB total ~8 us. Makes pass-2 weight staging a straight
// 16B DMA (no conversion) and halves all pass-2 read bytes.
__global__ __launch_bounds__(256)
void cvt_all(const float* __restrict__ x, const float* __restrict__ w,
             unsigned short* __restrict__ xb, unsigned short* __restrict__ wb) {
    const int nx4 = Bb * Cc * Ll / 4;          // 688,128 float4
    const int nw4 = NKk * Kk / 4;              // 677,376 float4
    const int t0 = blockIdx.x * 256 + threadIdx.x;
    const int st = gridDim.x * 256;
    for (int t = t0; t < nx4; t += st) {
        float4 v = ((const float4*)x)[t];
        ((ushort4*)xb)[t] = make_ushort4(f2bf(v.x), f2bf(v.y), f2bf(v.z), f2bf(v.w));
    }
    for (int t = t0; t < nw4; t += st) {
        float4 v = ((const float4*)w)[t];
        ((ushort4*)wb)[t] = make_ushort4(f2bf(v.x), f2bf(v.y), f2bf(v.z), f2bf(v.w));
    }
}

// ---- Pass 2: grid 512 = 252 windows x 2 batch-halves (8 tail idle). ----
// XCD grouping (R4): XCD r=bid%8 owns windows [32r,32r+32) -> 1.5 MB bf16
// x-slab L2-resident. Block: 256 thr = 4 waves, each one 16-row m-tile of a
// 64-row batch-half, full K=672 (21 MFMA) from a 21-frag register batch-issue.
// Weight tile (16x672 bf16) staged by global_load_lds DMA: 22 wave-issues of
// 1 KB into the KP=680-pitch layout (flat granule index g -> row g/85, col
// g%85, tail clamped into a pad region). Zero data-VGPRs, no cvt chain.
// Small block + 22.5 KB LDS + ~120 VGPR -> 2 blocks/CU co-resident: one
// stages while the other computes (the overlap R5's 1-block/CU grid lacked).
__global__ __launch_bounds__(256, 2)
void fb_mm(const unsigned short* __restrict__ xb,
           const unsigned short* __restrict__ wb,
           float* __restrict__ out) {
    __shared__ unsigned short ws[22 * 512];   // 22 KB: 16 rows x KP + DMA pad

    const int bid = blockIdx.x;
    const int r   = bid & 7;                  // XCD id (dispatch heuristic)
    const int t2  = bid >> 3;                 // 0..63 within XCD
    const int j   = r * 32 + (t2 >> 1);
    const int bh  = t2 & 1;                   // batch half
    if (j >= NWw) return;                     // uniform per block

    const int s    = (j < NWw - 1) ? j * Ss : (Ll - 32);  // STARTS[j], mult of 8
    const int tid  = threadIdx.x;
    const int lane = tid & 63;
    const int wv   = tid >> 6;       // 0..3: m-tile id
    const int col  = lane & 15;      // MFMA m-row (A) / n-col (B)
    const int quad = lane >> 4;      // k-chunk selector

    // ---- weight DMA: 1360 16B granules (+ clamped tail) in 22 wave-issues ----
    {
        const unsigned short* wj = wb + (size_t)j * (Oo * Kk);
        for (int iss = wv; iss < 22; iss += 4) {
            int g  = iss * 64 + lane;         // flat granule index
            int ro = g / 85;  if (ro > 15) ro = 15;
            int co = g - ro * 85; if (co > 83) co = 83;   // clamp pad granule
            const unsigned short* src = wj + ro * Kk + co * 8;
            __builtin_amdgcn_global_load_lds(
                (const __attribute__((address_space(1))) void*)src,
                (__attribute__((address_space(3))) void*)&ws[iss * 512],
                16, 0, 0);
        }
    }

    // ---- batch-issue all 21 A-fragments (bf16, 16B/lane, 16B-aligned) ----
    const unsigned short* xrow =
        xb + ((size_t)(bh * 64 + wv * 16 + col) * Cc) * Ll + s + quad * 8;
    short8 afr[Cc];
#pragma unroll
    for (int c = 0; c < Cc; ++c)
        afr[c] = *(const short8*)(xrow + (size_t)c * Ll);

    __syncthreads();   // drains DMA (vmcnt) + A-frags, publishes ws

    const unsigned short* wrow = &ws[col * KP + quad * 8];
    f32x4 acc = {0.f, 0.f, 0.f, 0.f};
#pragma unroll
    for (int c = 0; c < Cc; ++c)
        acc = __builtin_amdgcn_mfma_f32_16x16x32_bf16(
            afr[c], *(const short8*)(wrow + c * 32), acc, 0, 0, 0);

    // ---- C/D layout: col = lane&15, row = quad*4 + reg ----
    const int rbase = bh * 64 + wv * 16 + quad * 4;
    float* op = out + (size_t)rbase * NKk + j * 16 + col;
#pragma unroll
    for (int rr = 0; rr < 4; ++rr)
        op[(size_t)rr * NKk] = acc[rr];
}

extern "C" void kernel_launch(void* const* d_in, const int* in_sizes, int n_in,
                              void* d_out, int out_size, void* d_ws, size_t ws_size,
                              hipStream_t stream) {
    const float* x = (const float*)d_in[0];   // (128, 21, 2048) fp32
    const float* w = (const float*)d_in[1];   // (4032, 672) fp32
    float* out = (float*)d_out;               // (128, 4032) fp32
    unsigned short* xb = (unsigned short*)d_ws;                    // 11.0 MB bf16 x
    unsigned short* wb = (unsigned short*)d_ws + (size_t)Bb * Cc * Ll;  // 5.4 MB bf16 w
    cvt_all<<<dim3(2048), dim3(256), 0, stream>>>(x, w, xb, wb);
    fb_mm<<<dim3(512), dim3(256), 0, stream>>>(xb, wb, out);
}